// Round 8
// baseline (245.442 us; speedup 1.0000x reference)
//
#include <hip/hip_runtime.h>
#include <hip/hip_cooperative_groups.h>

namespace cg = cooperative_groups;

// ---- types ----
typedef _Float16 halfx8 __attribute__((ext_vector_type(8)));
typedef float floatx4 __attribute__((ext_vector_type(4)));

#define GLOBAL_AS __attribute__((address_space(1)))
#define LDS_AS __attribute__((address_space(3)))

// async global->LDS, 16B per lane; LDS dest = wave-uniform base + lane*16
__device__ __forceinline__ void async_copy_16(const void* g, void* l) {
    __builtin_amdgcn_global_load_lds((GLOBAL_AS void*)g, (LDS_AS void*)l, 16, 0, 0);
}

// problem dims
#define PM 16384
#define PD 768
#define PA 51

// Math identity (verified R5/R6): logits = x @ (Wa@We)^T + (Wa@b_embed + b_attr).
// h and logits are never materialized in global memory.
//
// ONE cooperative dispatch, 512 blocks x 256 threads:
//   Phase A: W_comb + b_comb + zero stats (block-owned, non-atomic)
//   grid.sync()
//   Phase B: skinny GEMM x @ Wc^T (R6-proven structure), logits in REGISTERS,
//            per-attr sum/sumsq -> LDS -> global atomics
//   grid.sync()
//   Phase C: BN scale/shift from stats, normalize registers, write out.
//
// R7 bug (fixed): async dest was &As[g*64]; each group is 256 floats -> g*256.

__global__ __launch_bounds__(256) void mega_kernel(
    const float* __restrict__ X,        // [16384][768]
    const float* __restrict__ We,       // [768][768]
    const float* __restrict__ Wa,       // [51][768]
    const float* __restrict__ b_embed,  // [768]
    const float* __restrict__ b_attr,   // [51]
    const float* __restrict__ gamma,    // [51]
    const float* __restrict__ beta,     // [51]
    float* __restrict__ out,            // [16384][51]
    float* __restrict__ wc32,           // ws: [64][768] fp32 (rows >= 51 zero)
    float* __restrict__ bc,             // ws: [64]
    float* __restrict__ stats)          // ws: [0..50]=sum, [64..114]=sumsq
{
    __shared__ __align__(16) char smem[25088];
    float* WaS   = (float*)smem;            // phase A: [768]
    float* red   = (float*)(smem + 3072);   // phase A: [256]
    float* As    = (float*)smem;            // phase B: [32][64] fp32 (8192 B)
    float* Bs    = (float*)(smem + 8192);   // phase B: [64][64] fp32 (16384 B)
    float* s_sum = (float*)(smem + 24576);  // [64]
    float* s_ssq = (float*)(smem + 24832);  // [64]

    cg::grid_group grid = cg::this_grid();
    const int tid = threadIdx.x;
    const int b = blockIdx.x;

    // ================= Phase A =================
    if (b < 306) {
        // wc32[a][d0..d0+127] = sum_k Wa[a][k] * We[k][d0..d0+127]
        int a = b / 6;
        int nc = b - a * 6;
        int d0 = nc * 128;
        if (tid < 192)
            *(floatx4*)&WaS[tid * 4] = *(const floatx4*)(Wa + (size_t)a * PD + tid * 4);
        __syncthreads();
        int c = tid & 127, h = tid >> 7;        // 128 cols x 2 k-halves
        const float* wep = We + (size_t)(h * 384) * PD + d0 + c;
        float acc = 0.f;
        #pragma unroll 8
        for (int k = 0; k < 384; ++k)
            acc += WaS[h * 384 + k] * wep[(size_t)k * PD];   // WaS: LDS broadcast
        red[tid] = acc;
        __syncthreads();
        if (h == 0)
            wc32[(size_t)a * PD + d0 + c] = red[c] + red[128 + c];
    } else if (b < 319) {
        // zero pad rows 51..63 (ws is re-poisoned every call!)
        int row = PA + (b - 306);
        for (int i = tid; i < PD; i += 256) wc32[(size_t)row * PD + i] = 0.f;
    } else if (b == 319) {
        if (tid < 128) stats[tid] = 0.f;
        // bc[a] = dot(Wa[a], b_embed) + b_attr[a]; 4 threads per attr
        int a = tid & 63, qtr = tid >> 6;
        float partial = 0.f;
        if (a < PA) {
            const float* war = Wa + (size_t)a * PD + qtr * 192;
            const float* ber = b_embed + qtr * 192;
            #pragma unroll 4
            for (int k = 0; k < 192; k += 4) {
                floatx4 w = *(const floatx4*)(war + k);
                floatx4 e = *(const floatx4*)(ber + k);
                partial += w[0]*e[0] + w[1]*e[1] + w[2]*e[2] + w[3]*e[3];
            }
        }
        red[tid] = partial;
        __syncthreads();
        if (tid < PA)
            bc[tid] = red[tid] + red[64 + tid] + red[128 + tid] + red[192 + tid] + b_attr[tid];
    }

    grid.sync();

    // ================= Phase B =================
    // 32 rows x 64 attrs per block. 4 waves: wave w -> rows (w&1)*16.., attrs (w>>1)*32..
    // A (x fp32) and B (wc32 fp32) staged via async global_load_lds, cvt fp16 at
    // LDS->reg. XOR swizzle (R2-verified 0 bank conflicts).
    const int wave = tid >> 6;
    const int lane = tid & 63;
    const int quad = lane >> 4;
    const int l16 = lane & 15;
    const int wr = wave & 1;
    const int wn = wave >> 1;
    const int row0 = b * 32;

    if (tid < 64) { s_sum[tid] = 0.f; s_ssq[tid] = 0.f; }

    const int g_r  = lane >> 4;         // 4 rows per 1KB async group
    const int g_sl = lane & 15;         // dest chunk slot 0..15

    floatx4 acc[2];
    acc[0] = (floatx4){0.f, 0.f, 0.f, 0.f};
    acc[1] = (floatx4){0.f, 0.f, 0.f, 0.f};

    for (int kt = 0; kt < PD; kt += 64) {
        #pragma unroll
        for (int j = 0; j < 2; ++j) {           // A: rows 0..31 (1KB = 256 floats/group)
            int g = wave * 2 + j;
            int r = g * 4 + g_r;
            int csrc = g_sl ^ (r & 7);
            async_copy_16(X + (size_t)(row0 + r) * PD + kt + csrc * 4, &As[g * 256]);
        }
        #pragma unroll
        for (int j = 0; j < 4; ++j) {           // B: rows 0..63
            int g = wave * 4 + j;
            int r = g * 4 + g_r;
            int csrc = g_sl ^ (r & 7);
            async_copy_16(wc32 + (size_t)r * PD + kt + csrc * 4, &Bs[g * 256]);
        }
        __syncthreads();
        #pragma unroll
        for (int ks = 0; ks < 2; ++ks) {
            int c0 = ks * 8 + quad * 2;
            int sw = l16 & 7;
            int rA = wr * 16 + l16;
            floatx4 p0 = *(const floatx4*)&As[rA * 64 + ((c0 ^ sw) << 2)];
            floatx4 p1 = *(const floatx4*)&As[rA * 64 + (((c0 + 1) ^ sw) << 2)];
            halfx8 af;
            af[0] = (_Float16)p0[0]; af[1] = (_Float16)p0[1];
            af[2] = (_Float16)p0[2]; af[3] = (_Float16)p0[3];
            af[4] = (_Float16)p1[0]; af[5] = (_Float16)p1[1];
            af[6] = (_Float16)p1[2]; af[7] = (_Float16)p1[3];
            #pragma unroll
            for (int ni = 0; ni < 2; ++ni) {
                int rB = wn * 32 + ni * 16 + l16;
                floatx4 q0 = *(const floatx4*)&Bs[rB * 64 + ((c0 ^ sw) << 2)];
                floatx4 q1 = *(const floatx4*)&Bs[rB * 64 + (((c0 + 1) ^ sw) << 2)];
                halfx8 bf;
                bf[0] = (_Float16)q0[0]; bf[1] = (_Float16)q0[1];
                bf[2] = (_Float16)q0[2]; bf[3] = (_Float16)q0[3];
                bf[4] = (_Float16)q1[0]; bf[5] = (_Float16)q1[1];
                bf[6] = (_Float16)q1[2]; bf[7] = (_Float16)q1[3];
                acc[ni] = __builtin_amdgcn_mfma_f32_16x16x32_f16(af, bf, acc[ni], 0, 0, 0);
            }
        }
        __syncthreads();
    }

    // epilogue: add bias in-register, accumulate stats. D col=n=attr, row=quad*4+r.
    #pragma unroll
    for (int ni = 0; ni < 2; ++ni) {
        int col = wn * 32 + ni * 16 + l16;
        if (col < PA) {
            float bv = bc[col];
            float ps = 0.f, pss = 0.f;
            #pragma unroll
            for (int r = 0; r < 4; ++r) {
                float v = acc[ni][r] + bv;
                acc[ni][r] = v;                 // logits live in registers
                ps += v; pss += v * v;
            }
            atomicAdd(&s_sum[col], ps);
            atomicAdd(&s_ssq[col], pss);
        }
    }
    __syncthreads();
    if (tid < PA) {
        atomicAdd(&stats[tid], s_sum[tid]);
        atomicAdd(&stats[64 + tid], s_ssq[tid]);
    }

    grid.sync();

    // ================= Phase C =================
    if (tid < PA) {
        const float invB = 1.0f / (float)PM;
        float mean = stats[tid] * invB;
        float var = stats[64 + tid] * invB - mean * mean;
        float inv = rsqrtf(var + 1e-5f);
        float g = gamma[tid] * inv;
        s_sum[tid] = g;                          // scale
        s_ssq[tid] = beta[tid] - mean * g;       // shift
    }
    __syncthreads();
    #pragma unroll
    for (int ni = 0; ni < 2; ++ni) {
        int col = wn * 32 + ni * 16 + l16;
        if (col < PA) {
            float sc = s_sum[col], sh = s_ssq[col];
            int rowb = row0 + wr * 16 + quad * 4;
            #pragma unroll
            for (int r = 0; r < 4; ++r)
                out[(size_t)(rowb + r) * PA + col] = acc[ni][r] * sc + sh;
        }
    }
}

// ------------------- launch -------------------
extern "C" void kernel_launch(void* const* d_in, const int* in_sizes, int n_in,
                              void* d_out, int out_size, void* d_ws, size_t ws_size,
                              hipStream_t stream) {
    const float* x       = (const float*)d_in[0];
    const float* W_embed = (const float*)d_in[1];
    const float* b_embed = (const float*)d_in[2];
    const float* W_attr  = (const float*)d_in[3];
    const float* b_attr  = (const float*)d_in[4];
    const float* gamma   = (const float*)d_in[5];
    const float* beta    = (const float*)d_in[6];
    float* out = (float*)d_out;

    char* ws = (char*)d_ws;
    float* wc32  = (float*)(ws);                  // 64*768*4 = 196608
    float* bc    = (float*)(ws + 196608);         // 64*4
    float* stats = (float*)(ws + 196864);         // 128*4

    // arg order matches kernel signature: X, We, Wa, b_embed, b_attr, gamma, beta,
    // out, wc32, bc, stats
    void* args[] = { (void*)&x, (void*)&W_embed, (void*)&W_attr, (void*)&b_embed,
                     (void*)&b_attr, (void*)&gamma, (void*)&beta, (void*)&out,
                     (void*)&wc32, (void*)&bc, (void*)&stats };
    hipLaunchCooperativeKernel((const void*)mega_kernel, dim3(512), dim3(256),
                               args, 0, stream);
}

// Round 10
// 214.453 us; speedup vs baseline: 1.1445x; 1.1445x over previous
//
#include <hip/hip_runtime.h>
#include <hip/hip_cooperative_groups.h>

namespace cg = cooperative_groups;

// ---- types ----
typedef _Float16 halfx8 __attribute__((ext_vector_type(8)));
typedef float floatx4 __attribute__((ext_vector_type(4)));

#define GLOBAL_AS __attribute__((address_space(1)))
#define LDS_AS __attribute__((address_space(3)))

// async global->LDS, 16B per lane; LDS dest = wave-uniform base + lane*16
__device__ __forceinline__ void async_copy_16(const void* g, void* l) {
    __builtin_amdgcn_global_load_lds((GLOBAL_AS void*)g, (LDS_AS void*)l, 16, 0, 0);
}

// problem dims
#define PM 16384
#define PD 768
#define PA 51

// Math identity (verified R5+): logits = x @ (Wa@We)^T + (Wa@b_embed + b_attr).
// h and logits never touch global memory.
//
// ONE cooperative dispatch, 256 blocks x 256 threads, 24576 B LDS
// (R9 lesson: 32768 B LDS made the coop launch fail silently -> all-zero out;
//  keep LDS < 25088 (R8-proven) and grid at 1 block/CU).
//  Phase A (78 blocks): wc16[4 attrs][128 cols] block-owned, LDS-staged We
//    tiles (async, coalesced), fp32 accumulate, fp16 store. Blocks 78..89 zero
//    pad rows 52..63 (attr group 12 writes a=51 as zeros), block 90 bc+stats.
//  grid.sync()
//  Phase B: skinny GEMM x @ wc16^T, TWO 32-row tiles per block (64 rows),
//    logits stay in REGISTERS; stats via LDS + global atomics.
//  grid.sync()
//  Phase C: BN normalize from registers, write out.

__global__ __launch_bounds__(256) void mega_kernel(
    const float* __restrict__ X,        // [16384][768]
    const float* __restrict__ We,       // [768][768]
    const float* __restrict__ Wa,       // [51][768]
    const float* __restrict__ b_embed,  // [768]
    const float* __restrict__ b_attr,   // [51]
    const float* __restrict__ gamma,    // [51]
    const float* __restrict__ beta,     // [51]
    float* __restrict__ out,            // [16384][51]
    _Float16* __restrict__ wc16,        // ws: [64][768] fp16 (rows >= 51 zero)
    float* __restrict__ bc,             // ws: [64]
    float* __restrict__ stats)          // ws: [0..50]=sum, [64..114]=sumsq
{
    __shared__ __align__(16) char smem[24576];
    // Phase A layout:
    float* WaS = (float*)smem;              // [4][768] fp32 = 12288 B
    float* WeS = (float*)(smem + 12288);    // [16][128] fp32 = 8192 B -> ends 20480
    float* red = (float*)(smem + 20480);    // [4][256] = 4096 B -> ends 24576
    // Phase B layout (reuses same LDS, only valid after grid.sync):
    float*    As    = (float*)smem;             // [32][64] fp32 = 8192 B
    _Float16* BsH   = (_Float16*)(smem + 8192); // [64][64] fp16 = 8192 B
    float*    s_sum = (float*)(smem + 16384);   // [64]
    float*    s_ssq = (float*)(smem + 16640);   // [64]

    cg::grid_group grid = cg::this_grid();
    const int tid = threadIdx.x;
    const int b = blockIdx.x;
    const int wave = tid >> 6;
    const int lane = tid & 63;

    // ================= Phase A =================
    if (b < 78) {
        int ag = b / 6;                  // attr group 0..12
        int nc = b - ag * 6;             // col chunk 0..5
        int a0 = ag * 4;
        int d0 = nc * 128;

        // stage 4 Wa rows (a >= PA -> zeros)
        if (tid < 192) {
            #pragma unroll
            for (int ai = 0; ai < 4; ++ai) {
                int a = a0 + ai;
                floatx4 v = (a < PA) ? *(const floatx4*)(Wa + (size_t)a * PD + tid * 4)
                                     : (floatx4){0.f, 0.f, 0.f, 0.f};
                *(floatx4*)&WaS[ai * 768 + tid * 4] = v;
            }
        }

        const int c = tid & 127;         // my output column within the 128-chunk
        const int h = tid >> 7;          // k-half (0/1) of each 16-chunk
        float a0c = 0.f, a1c = 0.f, a2c = 0.f, a3c = 0.f;

        for (int kt = 0; kt < PD; kt += 16) {
            // async-stage We[kt..kt+15][d0..d0+127]: 8 groups (2/wave), 1KB each
            #pragma unroll
            for (int j = 0; j < 2; ++j) {
                int g = wave * 2 + j;            // 0..7 -> rows 2g, 2g+1
                int row = g * 2 + (lane >> 5);
                int c16 = lane & 31;
                async_copy_16(We + (size_t)(kt + row) * PD + d0 + c16 * 4,
                              &WeS[g * 256]);
            }
            __syncthreads();
            #pragma unroll
            for (int kk = 0; kk < 8; ++kk) {
                int kidx = kt + h * 8 + kk;
                float w = WeS[(h * 8 + kk) * 128 + c];    // lanes consecutive
                a0c += WaS[kidx] * w;                     // broadcast reads
                a1c += WaS[768 + kidx] * w;
                a2c += WaS[1536 + kidx] * w;
                a3c += WaS[2304 + kidx] * w;
            }
            __syncthreads();
        }
        red[tid] = a0c; red[256 + tid] = a1c;
        red[512 + tid] = a2c; red[768 + tid] = a3c;
        __syncthreads();
        if (h == 0) {
            #pragma unroll
            for (int ai = 0; ai < 4; ++ai)
                wc16[(size_t)(a0 + ai) * PD + d0 + c] =
                    (_Float16)(red[ai * 256 + c] + red[ai * 256 + 128 + c]);
        }
    } else if (b < 90) {
        // zero pad rows 52..63 (ws re-poisoned every call; row 51 zeroed above)
        int row = 52 + (b - 78);
        for (int i = tid; i < PD; i += 256) wc16[(size_t)row * PD + i] = (_Float16)0.f;
    } else if (b == 90) {
        if (tid < 128) stats[tid] = 0.f;
        // bc[a] = dot(Wa[a], b_embed) + b_attr[a]; 4 threads per attr
        int a = tid & 63, qtr = tid >> 6;
        float partial = 0.f;
        if (a < PA) {
            const float* war = Wa + (size_t)a * PD + qtr * 192;
            const float* ber = b_embed + qtr * 192;
            #pragma unroll 4
            for (int k = 0; k < 192; k += 4) {
                floatx4 w = *(const floatx4*)(war + k);
                floatx4 e = *(const floatx4*)(ber + k);
                partial += w[0]*e[0] + w[1]*e[1] + w[2]*e[2] + w[3]*e[3];
            }
        }
        red[tid] = partial;
        __syncthreads();
        if (tid < PA)
            bc[tid] = red[tid] + red[64 + tid] + red[128 + tid] + red[192 + tid] + b_attr[tid];
    }

    grid.sync();

    // ================= Phase B =================
    // TWO 32-row x 64-attr tiles per block (rows b*64 .. b*64+63).
    // 4 waves: wave w -> rows (w&1)*16.., attrs (w>>1)*32..
    const int quad = lane >> 4;
    const int l16 = lane & 15;
    const int wr = wave & 1;
    const int wn = wave >> 1;

    if (tid < 64) { s_sum[tid] = 0.f; s_ssq[tid] = 0.f; }

    const int a_r  = lane >> 4;         // A: 4 rows per 1KB async group (fp32)
    const int a_sl = lane & 15;
    const int b_r  = lane >> 3;         // B: 8 rows per 1KB async group (fp16)
    const int b_sl = lane & 7;

    floatx4 acc[2][2];
    #pragma unroll
    for (int hf = 0; hf < 2; ++hf)
        #pragma unroll
        for (int ni = 0; ni < 2; ++ni)
            acc[hf][ni] = (floatx4){0.f, 0.f, 0.f, 0.f};

    #pragma unroll 1
    for (int hf = 0; hf < 2; ++hf) {
        const int row0 = b * 64 + hf * 32;
        for (int kt = 0; kt < PD; kt += 64) {
            #pragma unroll
            for (int j = 0; j < 2; ++j) {           // A: rows 0..31, fp32
                int g = wave * 2 + j;
                int r = g * 4 + a_r;
                int csrc = a_sl ^ (r & 7);
                async_copy_16(X + (size_t)(row0 + r) * PD + kt + csrc * 4, &As[g * 256]);
            }
            #pragma unroll
            for (int j = 0; j < 2; ++j) {           // B: rows 0..63, fp16
                int g = wave * 2 + j;               // 0..7 -> rows g*8..g*8+7
                int r = g * 8 + b_r;
                int csrc = b_sl ^ (r & 7);
                async_copy_16(wc16 + (size_t)r * PD + kt + csrc * 8, &BsH[g * 512]);
            }
            __syncthreads();
            #pragma unroll
            for (int ks = 0; ks < 2; ++ks) {
                int c0 = ks * 8 + quad * 2;
                int sw = l16 & 7;
                int rA = wr * 16 + l16;
                floatx4 p0 = *(const floatx4*)&As[rA * 64 + ((c0 ^ sw) << 2)];
                floatx4 p1 = *(const floatx4*)&As[rA * 64 + (((c0 + 1) ^ sw) << 2)];
                halfx8 af;
                af[0] = (_Float16)p0[0]; af[1] = (_Float16)p0[1];
                af[2] = (_Float16)p0[2]; af[3] = (_Float16)p0[3];
                af[4] = (_Float16)p1[0]; af[5] = (_Float16)p1[1];
                af[6] = (_Float16)p1[2]; af[7] = (_Float16)p1[3];
                #pragma unroll
                for (int ni = 0; ni < 2; ++ni) {
                    int rB = wn * 32 + ni * 16 + l16;
                    halfx8 bf = *(const halfx8*)&BsH[rB * 64 + (((ks * 4 + quad) ^ sw) << 3)];
                    acc[hf][ni] = __builtin_amdgcn_mfma_f32_16x16x32_f16(af, bf, acc[hf][ni], 0, 0, 0);
                }
            }
            __syncthreads();
        }
    }

    // epilogue: add bias in-register, accumulate stats. D col=n=attr, row=quad*4+r.
    #pragma unroll
    for (int hf = 0; hf < 2; ++hf) {
        #pragma unroll
        for (int ni = 0; ni < 2; ++ni) {
            int col = wn * 32 + ni * 16 + l16;
            if (col < PA) {
                float bv = bc[col];
                float ps = 0.f, pss = 0.f;
                #pragma unroll
                for (int r = 0; r < 4; ++r) {
                    float v = acc[hf][ni][r] + bv;
                    acc[hf][ni][r] = v;             // logits live in registers
                    ps += v; pss += v * v;
                }
                atomicAdd(&s_sum[col], ps);
                atomicAdd(&s_ssq[col], pss);
            }
        }
    }
    __syncthreads();
    if (tid < PA) {
        atomicAdd(&stats[tid], s_sum[tid]);
        atomicAdd(&stats[64 + tid], s_ssq[tid]);
    }

    grid.sync();

    // ================= Phase C =================
    if (tid < PA) {
        const float invB = 1.0f / (float)PM;
        float mean = stats[tid] * invB;
        float var = stats[64 + tid] * invB - mean * mean;
        float inv = rsqrtf(var + 1e-5f);
        float g = gamma[tid] * inv;
        s_sum[tid] = g;                          // scale
        s_ssq[tid] = beta[tid] - mean * g;       // shift
    }
    __syncthreads();
    #pragma unroll
    for (int hf = 0; hf < 2; ++hf) {
        #pragma unroll
        for (int ni = 0; ni < 2; ++ni) {
            int col = wn * 32 + ni * 16 + l16;
            if (col < PA) {
                float sc = s_sum[col], sh = s_ssq[col];
                int rowb = b * 64 + hf * 32 + wr * 16 + quad * 4;
                #pragma unroll
                for (int r = 0; r < 4; ++r)
                    out[(size_t)(rowb + r) * PA + col] = acc[hf][ni][r] * sc + sh;
            }
        }
    }
}

// ------------------- launch -------------------
extern "C" void kernel_launch(void* const* d_in, const int* in_sizes, int n_in,
                              void* d_out, int out_size, void* d_ws, size_t ws_size,
                              hipStream_t stream) {
    const float* x       = (const float*)d_in[0];
    const float* W_embed = (const float*)d_in[1];
    const float* b_embed = (const float*)d_in[2];
    const float* W_attr  = (const float*)d_in[3];
    const float* b_attr  = (const float*)d_in[4];
    const float* gamma   = (const float*)d_in[5];
    const float* beta    = (const float*)d_in[6];
    float* out = (float*)d_out;

    char* ws = (char*)d_ws;
    _Float16* wc16 = (_Float16*)(ws);             // 64*768*2 = 98304
    float*    bc   = (float*)(ws + 98304);        // 64*4
    float*    stats= (float*)(ws + 98560);        // 128*4

    // arg order matches kernel signature
    void* args[] = { (void*)&x, (void*)&W_embed, (void*)&W_attr, (void*)&b_embed,
                     (void*)&b_attr, (void*)&gamma, (void*)&beta, (void*)&out,
                     (void*)&wc16, (void*)&bc, (void*)&stats };
    hipLaunchCooperativeKernel((const void*)mega_kernel, dim3(256), dim3(256),
                               args, 0, stream);
}

// Round 11
// 136.609 us; speedup vs baseline: 1.7967x; 1.5698x over previous
//
#include <hip/hip_runtime.h>
#include <hip/hip_bf16.h>

// ---- types ----
typedef _Float16 halfx8 __attribute__((ext_vector_type(8)));
typedef float floatx4 __attribute__((ext_vector_type(4)));

#define GLOBAL_AS __attribute__((address_space(1)))
#define LDS_AS __attribute__((address_space(3)))

// async global->LDS, 16B per lane; LDS dest = wave-uniform base + lane*16
__device__ __forceinline__ void async_copy_16(const void* g, void* l) {
    __builtin_amdgcn_global_load_lds((GLOBAL_AS void*)g, (LDS_AS void*)l, 16, 0, 0);
}

// problem dims
#define PM 16384
#define PD 768
#define PA 51

// Math identity (verified R5+): logits = x @ (Wa@We)^T + (Wa@b_embed + b_attr).
// h never touches global memory.
// R10 lesson: cooperative grid.sync costs ~50-90 us on 8-XCD gfx950 (counters:
// 97% idle) -- separate dispatches (stream-ordered) are cheaper. 3 dispatches.

// ======== kernel 1: W_comb (fp16) + b_comb + zero stats, one dispatch ========
// blocks 0..77: block-owned (4 attrs x 128 cols), full K -- non-atomic, no
//   pre-zero needed (R10 phase-A structure, correctness-proven). attr group 12
//   covers a=48..51 and writes a=51 as zeros.
// block 78: zero wc16 rows 52..63.  block 79: bc + zero stats.
__global__ __launch_bounds__(256) void wcomb_kernel(
    const float* __restrict__ We,       // [768][768]
    const float* __restrict__ Wa,       // [51][768]
    const float* __restrict__ b_embed,  // [768]
    const float* __restrict__ b_attr,   // [51]
    _Float16* __restrict__ wc16,        // [64][768] fp16 out (rows >= 51 zero)
    float* __restrict__ bc,             // [64]
    float* __restrict__ stats)          // [0..50]=sum, [64..114]=sumsq
{
    __shared__ __align__(16) char smem[32768];
    float* WaS = (float*)smem;              // [4][768] = 12288 B
    float* WeS = (float*)(smem + 12288);    // [32][128] = 16384 B
    float* red = (float*)(smem + 28672);    // [4][256] = 4096 B (A-path reduction / bc)

    const int tid = threadIdx.x;
    const int b = blockIdx.x;
    const int wave = tid >> 6;
    const int lane = tid & 63;

    if (b < 78) {
        int ag = b / 6;                  // attr group 0..12
        int nc = b - ag * 6;             // col chunk 0..5
        int a0 = ag * 4;
        int d0 = nc * 128;

        // stage 4 Wa rows (a >= PA -> zeros)
        if (tid < 192) {
            #pragma unroll
            for (int ai = 0; ai < 4; ++ai) {
                int a = a0 + ai;
                floatx4 v = (a < PA) ? *(const floatx4*)(Wa + (size_t)a * PD + tid * 4)
                                     : (floatx4){0.f, 0.f, 0.f, 0.f};
                *(floatx4*)&WaS[ai * 768 + tid * 4] = v;
            }
        }

        const int c = tid & 127;         // my output column within the 128-chunk
        const int h = tid >> 7;          // k-half (0/1) of each 32-chunk
        float a0c = 0.f, a1c = 0.f, a2c = 0.f, a3c = 0.f;

        for (int kt = 0; kt < PD; kt += 32) {
            // async-stage We[kt..kt+31][d0..d0+127]: 16 groups (4/wave), 1KB each
            #pragma unroll
            for (int j = 0; j < 4; ++j) {
                int g = wave * 4 + j;            // 0..15 -> rows 2g, 2g+1
                int row = g * 2 + (lane >> 5);
                int c16 = lane & 31;
                async_copy_16(We + (size_t)(kt + row) * PD + d0 + c16 * 4,
                              &WeS[g * 256]);
            }
            __syncthreads();
            #pragma unroll
            for (int kk = 0; kk < 16; ++kk) {
                int kidx = kt + h * 16 + kk;
                float w = WeS[(h * 16 + kk) * 128 + c];   // lanes consecutive
                a0c += WaS[kidx] * w;                     // broadcast reads
                a1c += WaS[768 + kidx] * w;
                a2c += WaS[1536 + kidx] * w;
                a3c += WaS[2304 + kidx] * w;
            }
            __syncthreads();
        }
        red[tid] = a0c; red[256 + tid] = a1c;
        red[512 + tid] = a2c; red[768 + tid] = a3c;
        __syncthreads();
        if (h == 0) {
            #pragma unroll
            for (int ai = 0; ai < 4; ++ai)
                wc16[(size_t)(a0 + ai) * PD + d0 + c] =
                    (_Float16)(red[ai * 256 + c] + red[ai * 256 + 128 + c]);
        }
    } else if (b == 78) {
        // zero pad rows 52..63 (ws re-poisoned every call; row 51 zeroed above)
        halfx8 z;
        #pragma unroll
        for (int j = 0; j < 8; ++j) z[j] = (_Float16)0.f;
        for (int i = tid; i < 1152; i += 256)           // 12*768/8 = 1152 chunks
            *(halfx8*)(wc16 + (size_t)52 * PD + i * 8) = z;
    } else {
        if (tid < 128) stats[tid] = 0.f;
        // bc[a] = dot(Wa[a], b_embed) + b_attr[a]; 4 threads per attr (R6-proven)
        int a = tid & 63, qtr = tid >> 6;
        float partial = 0.f;
        if (a < PA) {
            const float* war = Wa + (size_t)a * PD + qtr * 192;
            const float* ber = b_embed + qtr * 192;
            #pragma unroll 4
            for (int k = 0; k < 192; k += 4) {
                floatx4 w = *(const floatx4*)(war + k);
                floatx4 e = *(const floatx4*)(ber + k);
                partial += w[0]*e[0] + w[1]*e[1] + w[2]*e[2] + w[3]*e[3];
            }
        }
        red[tid] = partial;
        __syncthreads();
        if (tid < PA)
            bc[tid] = red[tid] + red[64 + tid] + red[128 + tid] + red[192 + tid] + b_attr[tid];
    }
}

// ======== kernel 2: skinny GEMM logits = x @ wc16^T + bc, fused stats ========
// 512 blocks x 32 rows (R6-proven grid, 2 blocks/CU). 4 waves: wave w ->
// rows (w&1)*16.., attrs (w>>1)*32... A staged fp32 via async + cvt at LDS->reg;
// B staged fp16 direct (R10-proven). XOR swizzle: 0 bank conflicts (R2).
__global__ __launch_bounds__(256) void skinny_gemm_kernel(
    const float* __restrict__ X,        // [16384][768] fp32
    const _Float16* __restrict__ Wc,    // [64][768] fp16, rows >= 51 zero
    const float* __restrict__ bc,       // [64]
    float* __restrict__ logits,         // [16384][51]
    float* __restrict__ stats)          // [0..50]=sum, [64..114]=sumsq
{
    __shared__ __align__(16) char smem[17408];
    float*    As    = (float*)smem;             // [32][64] fp32 = 8192 B
    _Float16* BsH   = (_Float16*)(smem + 8192); // [64][64] fp16 = 8192 B
    float*    s_sum = (float*)(smem + 16384);   // [64]
    float*    s_ssq = (float*)(smem + 16640);   // [64]

    const int tid = threadIdx.x;
    const int wave = tid >> 6;
    const int lane = tid & 63;
    const int quad = lane >> 4;
    const int l16 = lane & 15;
    const int wr = wave & 1;
    const int wn = wave >> 1;
    const int row0 = blockIdx.x * 32;

    if (tid < 64) { s_sum[tid] = 0.f; s_ssq[tid] = 0.f; }

    const int a_r  = lane >> 4;         // A: 4 rows per 1KB async group (fp32)
    const int a_sl = lane & 15;
    const int b_r  = lane >> 3;         // B: 8 rows per 1KB async group (fp16)
    const int b_sl = lane & 7;

    floatx4 acc[2];
    acc[0] = (floatx4){0.f, 0.f, 0.f, 0.f};
    acc[1] = (floatx4){0.f, 0.f, 0.f, 0.f};

    for (int kt = 0; kt < PD; kt += 64) {
        #pragma unroll
        for (int j = 0; j < 2; ++j) {           // A: rows 0..31, fp32
            int g = wave * 2 + j;
            int r = g * 4 + a_r;
            int csrc = a_sl ^ (r & 7);
            async_copy_16(X + (size_t)(row0 + r) * PD + kt + csrc * 4, &As[g * 256]);
        }
        #pragma unroll
        for (int j = 0; j < 2; ++j) {           // B: rows 0..63, fp16
            int g = wave * 2 + j;               // 0..7 -> rows g*8..g*8+7
            int r = g * 8 + b_r;
            int csrc = b_sl ^ (r & 7);
            async_copy_16(Wc + (size_t)r * PD + kt + csrc * 8, &BsH[g * 512]);
        }
        __syncthreads();
        #pragma unroll
        for (int ks = 0; ks < 2; ++ks) {
            int c0 = ks * 8 + quad * 2;
            int sw = l16 & 7;
            int rA = wr * 16 + l16;
            floatx4 p0 = *(const floatx4*)&As[rA * 64 + ((c0 ^ sw) << 2)];
            floatx4 p1 = *(const floatx4*)&As[rA * 64 + (((c0 + 1) ^ sw) << 2)];
            halfx8 af;
            af[0] = (_Float16)p0[0]; af[1] = (_Float16)p0[1];
            af[2] = (_Float16)p0[2]; af[3] = (_Float16)p0[3];
            af[4] = (_Float16)p1[0]; af[5] = (_Float16)p1[1];
            af[6] = (_Float16)p1[2]; af[7] = (_Float16)p1[3];
            #pragma unroll
            for (int ni = 0; ni < 2; ++ni) {
                int rB = wn * 32 + ni * 16 + l16;
                halfx8 bf = *(const halfx8*)&BsH[rB * 64 + (((ks * 4 + quad) ^ sw) << 3)];
                acc[ni] = __builtin_amdgcn_mfma_f32_16x16x32_f16(af, bf, acc[ni], 0, 0, 0);
            }
        }
        __syncthreads();
    }

    // epilogue: D col (n) = attr, D row (m) = quad*4 + r (m89-verified layout)
    #pragma unroll
    for (int ni = 0; ni < 2; ++ni) {
        int col = wn * 32 + ni * 16 + l16;
        if (col < PA) {
            float bv = bc[col];
            float ps = 0.f, pss = 0.f;
            int rowb = row0 + wr * 16 + quad * 4;
            #pragma unroll
            for (int r = 0; r < 4; ++r) {
                float v = acc[ni][r] + bv;
                logits[(size_t)(rowb + r) * PA + col] = v;
                ps += v; pss += v * v;
            }
            atomicAdd(&s_sum[col], ps);
            atomicAdd(&s_ssq[col], pss);
        }
    }
    __syncthreads();
    if (tid < PA) {
        atomicAdd(&stats[tid], s_sum[tid]);
        atomicAdd(&stats[64 + tid], s_ssq[tid]);
    }
}

// ======== kernel 3: BN finalize, float4-vectorized ========
__global__ __launch_bounds__(256) void bn_finalize_kernel(
    const float* __restrict__ logits,
    const float* __restrict__ stats,
    const float* __restrict__ gamma,
    const float* __restrict__ beta,
    float* __restrict__ out)
{
    __shared__ float s_scale[PA];
    __shared__ float s_shift[PA];
    int t = threadIdx.x;
    if (t < PA) {
        const float invB = 1.0f / (float)PM;
        float mean = stats[t] * invB;
        float var = stats[64 + t] * invB - mean * mean;
        float inv = rsqrtf(var + 1e-5f);
        float g = gamma[t] * inv;
        s_scale[t] = g;
        s_shift[t] = beta[t] - mean * g;
    }
    __syncthreads();
    int idx4 = blockIdx.x * 256 + t;          // 816*256 = 208896 = 16384*51/4 exact
    floatx4 v = *(const floatx4*)(logits + (size_t)idx4 * 4);
    int base = (idx4 * 4) % PA;               // magic-mul
    floatx4 o;
    #pragma unroll
    for (int j = 0; j < 4; ++j) {
        int cj = base + j; if (cj >= PA) cj -= PA;
        o[j] = v[j] * s_scale[cj] + s_shift[cj];
    }
    *(floatx4*)(out + (size_t)idx4 * 4) = o;
}

// ------------------- launch -------------------
extern "C" void kernel_launch(void* const* d_in, const int* in_sizes, int n_in,
                              void* d_out, int out_size, void* d_ws, size_t ws_size,
                              hipStream_t stream) {
    const float* x       = (const float*)d_in[0];
    const float* W_embed = (const float*)d_in[1];
    const float* b_embed = (const float*)d_in[2];
    const float* W_attr  = (const float*)d_in[3];
    const float* b_attr  = (const float*)d_in[4];
    const float* gamma   = (const float*)d_in[5];
    const float* beta    = (const float*)d_in[6];
    float* out = (float*)d_out;

    char* ws = (char*)d_ws;
    _Float16* wc16   = (_Float16*)(ws);            // 64*768*2 = 98304
    float*    bc     = (float*)(ws + 98304);       // 64*4
    float*    stats  = (float*)(ws + 98560);       // 128*4
    float*    logits = (float*)(ws + 99072);       // 16384*51*4 = 3342336

    wcomb_kernel<<<80, 256, 0, stream>>>(W_embed, W_attr, b_embed, b_attr, wc16, bc, stats);
    skinny_gemm_kernel<<<512, 256, 0, stream>>>(x, wc16, bc, logits, stats);
    bn_finalize_kernel<<<816, 256, 0, stream>>>(logits, stats, gamma, beta, out);
}